// Round 13
// baseline (19.105 us; speedup 1.0000x reference)
//
#include <hip/hip_runtime.h>
#include <hip/hip_bf16.h>

#define BATCH 64
#define DIM 64
#define BANKN 131072

typedef __bf16 bf16x8 __attribute__((ext_vector_type(8)));
typedef __bf16 bf16x4 __attribute__((ext_vector_type(4)));
typedef float f32x16 __attribute__((ext_vector_type(16)));

__device__ inline bf16x8 pack_bf16x8(float4 a, float4 b) {
  bf16x8 r;
  r[0] = (__bf16)a.x; r[1] = (__bf16)a.y; r[2] = (__bf16)a.z; r[3] = (__bf16)a.w;
  r[4] = (__bf16)b.x; r[5] = (__bf16)b.y; r[6] = (__bf16)b.z; r[7] = (__bf16)b.w;
  return r;
}

// v9 = lean v7 body + DELIBERATE 2-GENERATION execution.
// Theory: v8 ran as ONE generation (grid == residency) -> all waves read,
// then all waves write: device-level phase serialization, K ~= r + w.
// Cap residency at 2 blocks/CU via dynamic-LDS padding (launch passes
// ~73 KB unused dynamic shared; static 8.4 KB -> ~80 KB/block). Grid 1024
// = exactly 2 generations of 512: gen-2 reads overlap gen-1 write drain.
// d^2 = qn[m] + 1 - 2C (bank rows unit-norm by construction); NT stores.
__global__ __launch_bounds__(256, 2) void mb_dist(const float* __restrict__ emb,
                                                  const float* __restrict__ bank,
                                                  float* __restrict__ out) {
  extern __shared__ char occupancy_pad[];  // unused; sized at launch to cap
                                           // residency at 2 blocks/CU
  __shared__ __align__(16) unsigned char s_emb[8192];
  __shared__ float s_qn[BATCH];

  const int tid  = threadIdx.x;
  const int lane = tid & 63;
  const int wave = tid >> 6;
  const int lr   = lane & 31;        // fragment row (bank) / C col
  const int lh   = lane >> 5;        // k-half
  const int q16  = (lane >> 4) & 3;  // 16-lane group id
  const int s16  = lane & 15;        // index within 16-lane group

  // ---- 1) bank: direct fragment-layout loads (HBM-critical, first) ----
  const int n0 = (blockIdx.x * 4 + wave) * 32;
  const float* brow = bank + (size_t)(n0 + lr) * DIM;
  float4 blo[4], bhi[4];
#pragma unroll
  for (int ks = 0; ks < 4; ++ks) {
    const float4* p = (const float4*)(brow + ks * 16 + lh * 8);
    blo[ks] = p[0];
    bhi[ks] = p[1];
  }

  // ---- 2) emb staging: 4 contiguous 4-KB loads across the block ----
  float4 ev[4];
#pragma unroll
  for (int j = 0; j < 4; ++j) ev[j] = ((const float4*)emb)[j * 256 + tid];

  // qn (exact fp32): 16 consecutive lanes hold one emb row
#pragma unroll
  for (int j = 0; j < 4; ++j) {
    float4 v = ev[j];
    float sq = fmaf(v.x, v.x, fmaf(v.y, v.y, fmaf(v.z, v.z, v.w * v.w)));
    sq += __shfl_xor(sq, 1); sq += __shfl_xor(sq, 2);
    sq += __shfl_xor(sq, 4); sq += __shfl_xor(sq, 8);
    if (s16 == 0) s_qn[j * 16 + wave * 4 + q16] = sq;
  }

  // emb -> bf16 fragment-linear LDS
#pragma unroll
  for (int j = 0; j < 4; ++j) {
    const int gsrc = j * 256 + tid;
    const int row = gsrc >> 4, colg = gsrc & 15;
    const int mt = row >> 5, r5 = row & 31;
    const int ks = colg >> 2, lhh = (colg >> 1) & 1, p = colg & 1;
    bf16x4 c;
    c[0] = (__bf16)ev[j].x; c[1] = (__bf16)ev[j].y;
    c[2] = (__bf16)ev[j].z; c[3] = (__bf16)ev[j].w;
    const int off = ((mt * 4 + ks) * 2 + lhh) * 512 + r5 * 16 + p * 8;
    *(bf16x4*)(s_emb + off) = c;
  }

  __syncthreads();  // only barrier

  // ---- 3) A fragments: 8 conflict-free ds_read_b128 ----
  bf16x8 afr[2][4];
#pragma unroll
  for (int mt = 0; mt < 2; ++mt)
#pragma unroll
    for (int ks = 0; ks < 4; ++ks)
      afr[mt][ks] = *(const bf16x8*)(s_emb + (mt * 4 + ks) * 1024 + lane * 16);

  // ---- 4) B fragments ----
  bf16x8 bfr[4];
#pragma unroll
  for (int ks = 0; ks < 4; ++ks) bfr[ks] = pack_bf16x8(blo[ks], bhi[ks]);

  // ---- 5) MFMA ----
  f32x16 acc0, acc1;
#pragma unroll
  for (int i = 0; i < 16; ++i) { acc0[i] = 0.f; acc1[i] = 0.f; }
#pragma unroll
  for (int ks = 0; ks < 4; ++ks) {
    acc0 = __builtin_amdgcn_mfma_f32_32x32x16_bf16(afr[0][ks], bfr[ks], acc0, 0, 0, 0);
    acc1 = __builtin_amdgcn_mfma_f32_32x32x16_bf16(afr[1][ks], bfr[ks], acc1, 0, 0, 0);
  }

  // ---- 6) epilogue: d = sqrt(qn[row] + 1 - 2C), direct NT stores ----
  const int ncol = n0 + lr;
#pragma unroll
  for (int reg = 0; reg < 16; ++reg) {
    const int rr = (reg & 3) + 8 * (reg >> 2) + 4 * lh;
    {
      float d2 = fmaf(-2.f, acc0[reg], s_qn[rr] + 1.0f);
      __builtin_nontemporal_store(sqrtf(fmaxf(d2, 0.f)),
                                  out + (size_t)rr * BANKN + ncol);
    }
    {
      float d2 = fmaf(-2.f, acc1[reg], s_qn[32 + rr] + 1.0f);
      __builtin_nontemporal_store(sqrtf(fmaxf(d2, 0.f)),
                                  out + (size_t)(32 + rr) * BANKN + ncol);
    }
  }
}

extern "C" void kernel_launch(void* const* d_in, const int* in_sizes, int n_in,
                              void* d_out, int out_size, void* d_ws, size_t ws_size,
                              hipStream_t stream) {
  const float* emb  = (const float*)d_in[0];
  const float* bank = (const float*)d_in[1];
  float* out = (float*)d_out;
  // 1024 blocks x 256 threads; 4 waves x 32 bank rows per block.
  // Dynamic shared 72704 B (unused) + ~8.4 KB static ~= 80 KB/block
  // -> exactly 2 blocks/CU resident -> 2 generations of 512 blocks.
  mb_dist<<<dim3(BANKN / 128), dim3(256), 72704, stream>>>(emb, bank, out);
}